// Round 1
// baseline (486.024 us; speedup 1.0000x reference)
//
#include <hip/hip_runtime.h>

typedef __attribute__((ext_vector_type(8))) short short8;
typedef __attribute__((ext_vector_type(4))) float f32x4;

#define MROWS 16
#define NSTEPS 16

// ws layout per bijector (ushort units):
//   W1f: [ks2][nt16][lane64][j8] = 16384 @ 0        (t-row excluded; k=0..63)
//   W2f: [ks8][nt16][lane64][j8] = 65536 @ 16384
//   W3f: [ks8][nt4 ][lane64][j8] = 16384 @ 81920
// per-bijector total 98304 ushorts (192 KB); x2 bijectors = 384 KB of d_ws.

__device__ __forceinline__ unsigned short bf16rne(float f) {
  unsigned int u = __float_as_uint(f);
  u += 0x7FFFu + ((u >> 16) & 1u);
  return (unsigned short)(u >> 16);
}

__device__ __forceinline__ float tanh_fast(float x) {
  x = fminf(12.0f, fmaxf(-12.0f, x));
  float e = __builtin_amdgcn_exp2f(x * 2.8853900817779268f); // e^{2x}
  return (e - 1.0f) * __builtin_amdgcn_rcpf(e + 1.0f);
}

// Pre-shuffle fp32 weights -> bf16 MFMA B-operand fragments.
// B-frag for 16x16x32: lane holds B[k = 32*ks + 8*(lane>>4) + j][n = 16*nt + (lane&15)], j=0..7
__global__ void ffjord_setup(const float* __restrict__ W1a, const float* __restrict__ W2a,
                             const float* __restrict__ W3a, const float* __restrict__ W1b,
                             const float* __restrict__ W2b, const float* __restrict__ W3b,
                             unsigned short* __restrict__ ws) {
  int gid = blockIdx.x * blockDim.x + threadIdx.x;   // 0..24575
  int bij = gid / 12288;
  int r = gid - bij * 12288;
  const float* W1 = bij ? W1b : W1a;
  const float* W2 = bij ? W2b : W2a;
  const float* W3 = bij ? W3b : W3a;
  unsigned short* o = ws + bij * 98304;
  const float* src;
  int kstride;
  if (r < 2048) {                 // W1f
    int lane = r & 63, nt = (r >> 6) & 15, ks = r >> 10;
    int k0 = ks * 32 + (lane >> 4) * 8, n = nt * 16 + (lane & 15);
    src = W1 + k0 * 256 + n; kstride = 256; o += r * 8;
  } else if (r < 10240) {         // W2f
    int rr = r - 2048;
    int lane = rr & 63, nt = (rr >> 6) & 15, ks = rr >> 10;
    int k0 = ks * 32 + (lane >> 4) * 8, n = nt * 16 + (lane & 15);
    src = W2 + k0 * 256 + n; kstride = 256; o += 16384 + rr * 8;
  } else {                        // W3f
    int rr = r - 10240;
    int lane = rr & 63, nt = (rr >> 6) & 3, ks = rr >> 8;
    int k0 = ks * 32 + (lane >> 4) * 8, n = nt * 16 + (lane & 15);
    src = W3 + k0 * 64 + n; kstride = 64; o += 81920 + rr * 8;
  }
  #pragma unroll
  for (int j = 0; j < 8; j++) o[j] = bf16rne(src[j * kstride]);
}

// One block = 16 batch rows, runs the full 2-bijector / 16-step / 6-stage chain.
// 4 waves split output columns; W2 frags LDS-resident, W1/W3 frags in registers.
__global__ __launch_bounds__(256) void ffjord_main(
    const float* __restrict__ x, float* __restrict__ out,
    const unsigned short* __restrict__ ws,
    const float* __restrict__ W1a, const float* __restrict__ b1a,
    const float* __restrict__ b2a, const float* __restrict__ b3a,
    const float* __restrict__ W1b, const float* __restrict__ b1b,
    const float* __restrict__ b2b, const float* __restrict__ b3b) {
  __shared__ __align__(16) unsigned short w2f[65536]; // 128 KB
  __shared__ __align__(16) unsigned short zA[1024];   // stage input, A-frag-major (K=64)
  __shared__ __align__(16) unsigned short h1A[4096];  // layer-1 out, A-frag-major (K=256)
  __shared__ __align__(16) unsigned short h2A[4096];  // layer-2 out, A-frag-major
  __shared__ __align__(16) float fbuf[1024];          // MLP output (row-major 16x64)
  __shared__ __align__(16) float b1eff[256];          // b1 + t*W1[64,:]

  const int tid = threadIdx.x;
  const int wave = tid >> 6;
  const int lane = tid & 63;
  const int cl = lane & 15;
  const int qd = lane >> 4;
  const int row0 = blockIdx.x * MROWS;
  const int rown = tid >> 4;        // state row owned by this thread (0..15)
  const int d0 = (tid & 15) * 4;    // first of 4 state cols owned

  const float hstep = 1.0f / 16.0f;

  float y[4];
  {
    float4 v = *(const float4*)(x + (row0 + rown) * 64 + d0);
    y[0] = v.x; y[1] = v.y; y[2] = v.z; y[3] = v.w;
  }
  float k[6][4];

  // A-frag-major address for this thread's 4 consecutive z elements
  const int zoff = (d0 >> 5) * 512 + (rown + 16 * ((d0 & 31) >> 3)) * 8 + (d0 & 7);

  const float ACO[6][5] = {
      {0.f, 0.f, 0.f, 0.f, 0.f},
      {1.f / 5.f, 0.f, 0.f, 0.f, 0.f},
      {3.f / 40.f, 9.f / 40.f, 0.f, 0.f, 0.f},
      {44.f / 45.f, -56.f / 15.f, 32.f / 9.f, 0.f, 0.f},
      {19372.f / 6561.f, -25360.f / 2187.f, 64448.f / 6561.f, -212.f / 729.f, 0.f},
      {9017.f / 3168.f, -355.f / 33.f, 46732.f / 5247.f, 49.f / 176.f, -5103.f / 18656.f}};
  const float CT[6] = {0.0f, 0.2f, 0.3f, 0.8f, 8.0f / 9.0f, 1.0f};
  const float BW0 = 35.f / 384.f, BW2 = 500.f / 1113.f, BW3 = 125.f / 192.f,
              BW4 = -2187.f / 6784.f, BW5 = 11.f / 84.f;

  for (int bij = 0; bij < 2; bij++) {
    const unsigned short* wsb = ws + bij * 98304;
    const float* W1 = bij ? W1b : W1a;
    const float* b1 = bij ? b1b : b1a;
    const float* b2 = bij ? b2b : b2a;
    const float* b3 = bij ? b3b : b3a;

    // per-thread constants
    float b1r = b1[tid];
    float w1tr = W1[64 * 256 + tid];   // t-row of W1
    float b2r[4];
    #pragma unroll
    for (int j = 0; j < 4; j++) b2r[j] = b2[(wave * 4 + j) * 16 + cl];
    float b3r = b3[wave * 16 + cl];

    // register-resident W1/W3 fragments
    short8 w1f[2][4];
    #pragma unroll
    for (int ks = 0; ks < 2; ks++)
      #pragma unroll
      for (int j = 0; j < 4; j++)
        w1f[ks][j] = ((const short8*)wsb)[(ks * 16 + wave * 4 + j) * 64 + lane];
    short8 w3f[8];
    #pragma unroll
    for (int ks = 0; ks < 8; ks++)
      w3f[ks] = ((const short8*)(wsb + 81920))[(ks * 4 + wave) * 64 + lane];

    // stage W2 fragments into LDS (once per bijector)
    {
      const uint4* s4 = (const uint4*)(wsb + 16384);
      uint4* dst = (uint4*)w2f;
      #pragma unroll
      for (int i = 0; i < 32; i++) dst[tid + 256 * i] = s4[tid + 256 * i];
    }
    __syncthreads();

    for (int step = 0; step < NSTEPS; step++) {
      float stepf = (float)step;
      #pragma unroll
      for (int s = 0; s < 6; s++) {
        float ts = (stepf + CT[s]) * hstep;

        // ---- phase 1: stage input z = y + h*sum(a_sj * k_j), write bf16 A-frags
        {
          float zv[4];
          #pragma unroll
          for (int i = 0; i < 4; i++) {
            float z = y[i];
            #pragma unroll
            for (int j = 0; j < 5; j++)
              if (j < s) z += (hstep * ACO[s][j]) * k[j][i];
            zv[i] = z;
          }
          ushort4 p;
          p.x = bf16rne(zv[0]); p.y = bf16rne(zv[1]);
          p.z = bf16rne(zv[2]); p.w = bf16rne(zv[3]);
          *(ushort4*)(zA + zoff) = p;
          b1eff[tid] = b1r + ts * w1tr;
        }
        __syncthreads();

        // ---- layer 1: h1 = tanh(z @ W1[:64] + b1eff), K=64
        {
          short8 a0 = ((const short8*)zA)[lane];
          short8 a1 = ((const short8*)zA)[64 + lane];
          #pragma unroll
          for (int j = 0; j < 4; j++) {
            f32x4 acc = {0.f, 0.f, 0.f, 0.f};
            acc = __builtin_amdgcn_mfma_f32_16x16x32_bf16(a0, w1f[0][j], acc, 0, 0, 0);
            acc = __builtin_amdgcn_mfma_f32_16x16x32_bf16(a1, w1f[1][j], acc, 0, 0, 0);
            int c = (wave * 4 + j) * 16 + cl;
            float be = b1eff[c];
            int boff = (c >> 5) * 512 + 16 * ((c & 31) >> 3) * 8 + (c & 7);
            #pragma unroll
            for (int reg = 0; reg < 4; reg++)
              h1A[boff + (4 * qd + reg) * 8] = bf16rne(tanh_fast(acc[reg] + be));
          }
        }
        __syncthreads();

        // ---- layer 2: h2 = tanh(h1 @ W2 + b2), K=256
        {
          f32x4 zero = {0.f, 0.f, 0.f, 0.f};
          f32x4 acc2[4] = {zero, zero, zero, zero};
          #pragma unroll
          for (int ks = 0; ks < 8; ks++) {
            short8 a = ((const short8*)h1A)[ks * 64 + lane];
            #pragma unroll
            for (int j = 0; j < 4; j++) {
              short8 b = ((const short8*)w2f)[(ks * 16 + wave * 4 + j) * 64 + lane];
              acc2[j] = __builtin_amdgcn_mfma_f32_16x16x32_bf16(a, b, acc2[j], 0, 0, 0);
            }
          }
          #pragma unroll
          for (int j = 0; j < 4; j++) {
            int c = (wave * 4 + j) * 16 + cl;
            int boff = (c >> 5) * 512 + 16 * ((c & 31) >> 3) * 8 + (c & 7);
            #pragma unroll
            for (int reg = 0; reg < 4; reg++)
              h2A[boff + (4 * qd + reg) * 8] = bf16rne(tanh_fast(acc2[j][reg] + b2r[j]));
          }
        }
        __syncthreads();

        // ---- layer 3: f = h2 @ W3 + b3, K=256, N=64 (one 16-col tile per wave)
        {
          f32x4 acc3 = {0.f, 0.f, 0.f, 0.f};
          #pragma unroll
          for (int ks = 0; ks < 8; ks++) {
            short8 a = ((const short8*)h2A)[ks * 64 + lane];
            acc3 = __builtin_amdgcn_mfma_f32_16x16x32_bf16(a, w3f[ks], acc3, 0, 0, 0);
          }
          int c = wave * 16 + cl;
          #pragma unroll
          for (int reg = 0; reg < 4; reg++)
            fbuf[(4 * qd + reg) * 64 + c] = acc3[reg] + b3r;
        }
        __syncthreads();

        // ---- phase 5: pull k_s back to registers (fp32)
        {
          float4 kv = *(const float4*)(fbuf + 4 * tid);
          k[s][0] = kv.x; k[s][1] = kv.y; k[s][2] = kv.z; k[s][3] = kv.w;
        }
      } // stages

      #pragma unroll
      for (int i = 0; i < 4; i++) {
        float d = BW0 * k[0][i] + BW2 * k[2][i] + BW3 * k[3][i] +
                  BW4 * k[4][i] + BW5 * k[5][i];
        y[i] += hstep * d;
      }
    } // steps
  } // bijectors

  *(float4*)(out + (row0 + rown) * 64 + d0) = make_float4(y[0], y[1], y[2], y[3]);
}

extern "C" void kernel_launch(void* const* d_in, const int* in_sizes, int n_in,
                              void* d_out, int out_size, void* d_ws, size_t ws_size,
                              hipStream_t stream) {
  (void)in_sizes; (void)n_in; (void)out_size; (void)ws_size;
  const float* x   = (const float*)d_in[0];
  const float* W1a = (const float*)d_in[1];
  const float* b1a = (const float*)d_in[2];
  const float* W2a = (const float*)d_in[3];
  const float* b2a = (const float*)d_in[4];
  const float* W3a = (const float*)d_in[5];
  const float* b3a = (const float*)d_in[6];
  const float* W1b = (const float*)d_in[7];
  const float* b1b = (const float*)d_in[8];
  const float* W2b = (const float*)d_in[9];
  const float* b2b = (const float*)d_in[10];
  const float* W3b = (const float*)d_in[11];
  const float* b3b = (const float*)d_in[12];
  unsigned short* ws = (unsigned short*)d_ws;
  float* out = (float*)d_out;

  hipLaunchKernelGGL(ffjord_setup, dim3(96), dim3(256), 0, stream,
                     W1a, W2a, W3a, W1b, W2b, W3b, ws);
  hipLaunchKernelGGL(ffjord_main, dim3(256), dim3(256), 0, stream,
                     x, out, ws, W1a, b1a, b2a, b3a, W1b, b1b, b2b, b3b);
}

// Round 2
// 348.013 us; speedup vs baseline: 1.3966x; 1.3966x over previous
//
#include <hip/hip_runtime.h>

typedef __attribute__((ext_vector_type(8))) short short8;
typedef __attribute__((ext_vector_type(4))) float f32x4;

#define MROWS 16
#define NSTEPS 16

// ws layout per bijector (ushort units):
//   W1f: [ks2][nt16][lane64][j8] = 16384 @ 0        (t-row excluded; k=0..63)
//   W2f: [ks8][nt16][lane64][j8] = 65536 @ 16384
//   W3f: [ks8][nt4 ][lane64][j8] = 16384 @ 81920
// per-bijector total 98304 ushorts (192 KB); x2 bijectors = 384 KB of d_ws.

__device__ __forceinline__ unsigned short bf16rne(float f) {
  unsigned int u = __float_as_uint(f);
  u += 0x7FFFu + ((u >> 16) & 1u);
  return (unsigned short)(u >> 16);
}

__device__ __forceinline__ float tanh_fast(float x) {
  // tanh(x) = 1 - 2/(e^{2x}+1); only upper clamp needed (e->0 is fine)
  x = fminf(12.0f, x);
  float e = __builtin_amdgcn_exp2f(x * 2.8853900817779268f); // e^{2x}
  return __builtin_fmaf(-2.0f, __builtin_amdgcn_rcpf(e + 1.0f), 1.0f);
}

// Pre-shuffle fp32 weights -> bf16 MFMA B-operand fragments.
// B-frag for 16x16x32: lane holds B[k = 32*ks + 8*(lane>>4) + j][n = 16*nt + (lane&15)], j=0..7
__global__ void ffjord_setup(const float* __restrict__ W1a, const float* __restrict__ W2a,
                             const float* __restrict__ W3a, const float* __restrict__ W1b,
                             const float* __restrict__ W2b, const float* __restrict__ W3b,
                             unsigned short* __restrict__ ws) {
  int gid = blockIdx.x * blockDim.x + threadIdx.x;   // 0..24575
  int bij = gid / 12288;
  int r = gid - bij * 12288;
  const float* W1 = bij ? W1b : W1a;
  const float* W2 = bij ? W2b : W2a;
  const float* W3 = bij ? W3b : W3a;
  unsigned short* o = ws + bij * 98304;
  const float* src;
  int kstride;
  if (r < 2048) {                 // W1f
    int lane = r & 63, nt = (r >> 6) & 15, ks = r >> 10;
    int k0 = ks * 32 + (lane >> 4) * 8, n = nt * 16 + (lane & 15);
    src = W1 + k0 * 256 + n; kstride = 256; o += r * 8;
  } else if (r < 10240) {         // W2f
    int rr = r - 2048;
    int lane = rr & 63, nt = (rr >> 6) & 15, ks = rr >> 10;
    int k0 = ks * 32 + (lane >> 4) * 8, n = nt * 16 + (lane & 15);
    src = W2 + k0 * 256 + n; kstride = 256; o += 16384 + rr * 8;
  } else {                        // W3f
    int rr = r - 10240;
    int lane = rr & 63, nt = (rr >> 6) & 3, ks = rr >> 8;
    int k0 = ks * 32 + (lane >> 4) * 8, n = nt * 16 + (lane & 15);
    src = W3 + k0 * 64 + n; kstride = 64; o += 81920 + rr * 8;
  }
  #pragma unroll
  for (int j = 0; j < 8; j++) o[j] = bf16rne(src[j * kstride]);
}

// One block = 16 batch rows, 512 threads (8 waves), runs the full chain.
// Each wave owns a 32-col slice of layers 1/2 (W1/W2 frags register-resident);
// layer 3 is K-split across wave pairs (fbufA + fbufB summed at readback).
__global__ __launch_bounds__(512, 2) void ffjord_main(
    const float* __restrict__ x, float* __restrict__ out,
    const unsigned short* __restrict__ ws,
    const float* __restrict__ W1a, const float* __restrict__ b1a,
    const float* __restrict__ b2a, const float* __restrict__ b3a,
    const float* __restrict__ W1b, const float* __restrict__ b1b,
    const float* __restrict__ b2b, const float* __restrict__ b3b) {
  __shared__ __align__(16) unsigned short zA[1024];   // stage input, A-frag-major (K=64)
  __shared__ __align__(16) unsigned short h1A[4096];  // layer-1 out, A-frag-major (K=256)
  __shared__ __align__(16) unsigned short h2A[4096];  // layer-2 out, A-frag-major
  __shared__ __align__(16) float fbufA[16 * 68];      // L3 partial (ks 0-3), row stride 68
  __shared__ __align__(16) float fbufB[16 * 68];      // L3 partial (ks 4-7)

  const int tid = threadIdx.x;
  const int wave = tid >> 6;       // 0..7
  const int lane = tid & 63;
  const int cl = lane & 15;
  const int qd = lane >> 4;
  const int w4 = wave & 3;
  const int ksb = (wave >> 2) * 4; // 0 or 4 (L3 K-split base)
  const int row0 = blockIdx.x * MROWS;
  const int rown = tid >> 5;       // state row owned by this thread (0..15)
  const int d0 = (tid & 31) * 2;   // first of 2 state cols owned

  const float hstep = 1.0f / 16.0f;

  float y[2];
  {
    float2 v = *(const float2*)(x + (row0 + rown) * 64 + d0);
    y[0] = v.x; y[1] = v.y;
  }
  float k[6][2];

  // A-frag-major address for this thread's 2 consecutive z elements
  const int zoff = (d0 >> 5) * 512 + (rown + 16 * ((d0 & 31) >> 3)) * 8 + (d0 & 7);

  const float ACO[6][5] = {
      {0.f, 0.f, 0.f, 0.f, 0.f},
      {1.f / 5.f, 0.f, 0.f, 0.f, 0.f},
      {3.f / 40.f, 9.f / 40.f, 0.f, 0.f, 0.f},
      {44.f / 45.f, -56.f / 15.f, 32.f / 9.f, 0.f, 0.f},
      {19372.f / 6561.f, -25360.f / 2187.f, 64448.f / 6561.f, -212.f / 729.f, 0.f},
      {9017.f / 3168.f, -355.f / 33.f, 46732.f / 5247.f, 49.f / 176.f, -5103.f / 18656.f}};
  const float CT[6] = {0.0f, 0.2f, 0.3f, 0.8f, 8.0f / 9.0f, 1.0f};
  const float BW0 = 35.f / 384.f, BW2 = 500.f / 1113.f, BW3 = 125.f / 192.f,
              BW4 = -2187.f / 6784.f, BW5 = 11.f / 84.f;

  for (int bij = 0; bij < 2; bij++) {
    const unsigned short* wsb = ws + bij * 98304;
    const float* W1 = bij ? W1b : W1a;
    const float* b1 = bij ? b1b : b1a;
    const float* b2 = bij ? b2b : b2a;
    const float* b3 = bij ? b3b : b3a;

    // per-thread scalar constants for this wave's 2 column tiles
    float b1c[2], w1tc[2], b2r[2];
    #pragma unroll
    for (int j = 0; j < 2; j++) {
      int c = (wave * 2 + j) * 16 + cl;
      b1c[j] = b1[c];
      w1tc[j] = W1[64 * 256 + c];   // t-row of W1
      b2r[j] = b2[c];
    }
    float b3r = (wave < 4) ? b3[w4 * 16 + cl] : 0.0f;

    // register-resident weight fragments
    const short8* w1p = (const short8*)wsb;
    const short8* w2p = (const short8*)(wsb + 16384);
    const short8* w3p = (const short8*)(wsb + 81920);
    short8 w1f[2][2];
    #pragma unroll
    for (int ks = 0; ks < 2; ks++)
      #pragma unroll
      for (int j = 0; j < 2; j++)
        w1f[ks][j] = w1p[(ks * 16 + wave * 2 + j) * 64 + lane];
    short8 w2f[8][2];
    #pragma unroll
    for (int ks = 0; ks < 8; ks++)
      #pragma unroll
      for (int j = 0; j < 2; j++)
        w2f[ks][j] = w2p[(ks * 16 + wave * 2 + j) * 64 + lane];
    short8 w3f[4];
    #pragma unroll
    for (int kk = 0; kk < 4; kk++)
      w3f[kk] = w3p[((ksb + kk) * 4 + w4) * 64 + lane];

    for (int step = 0; step < NSTEPS; step++) {
      float stepf = (float)step;
      #pragma unroll
      for (int s = 0; s < 6; s++) {
        float ts = (stepf + CT[s]) * hstep;

        // ---- phase 1: z = y + h*sum(a_sj * k_j), write bf16 A-frags
        {
          float z0 = y[0], z1 = y[1];
          #pragma unroll
          for (int j = 0; j < 5; j++)
            if (j < s) {
              float a = hstep * ACO[s][j];
              z0 += a * k[j][0];
              z1 += a * k[j][1];
            }
          ushort2 p;
          p.x = bf16rne(z0); p.y = bf16rne(z1);
          *(ushort2*)(zA + zoff) = p;
        }
        __syncthreads();

        // ---- layer 1: h1 = tanh(z @ W1[:64] + b1 + t*W1t), K=64
        {
          short8 a0 = ((const short8*)zA)[lane];
          short8 a1 = ((const short8*)zA)[64 + lane];
          #pragma unroll
          for (int j = 0; j < 2; j++) {
            f32x4 acc = {0.f, 0.f, 0.f, 0.f};
            acc = __builtin_amdgcn_mfma_f32_16x16x32_bf16(a0, w1f[0][j], acc, 0, 0, 0);
            acc = __builtin_amdgcn_mfma_f32_16x16x32_bf16(a1, w1f[1][j], acc, 0, 0, 0);
            int c = (wave * 2 + j) * 16 + cl;
            float be = __builtin_fmaf(ts, w1tc[j], b1c[j]);
            int boff = (c >> 5) * 512 + ((c & 31) >> 3) * 128 + (c & 7);
            #pragma unroll
            for (int reg = 0; reg < 4; reg++)
              h1A[boff + (4 * qd + reg) * 8] = bf16rne(tanh_fast(acc[reg] + be));
          }
        }
        __syncthreads();

        // ---- layer 2: h2 = tanh(h1 @ W2 + b2), K=256
        {
          f32x4 zero = {0.f, 0.f, 0.f, 0.f};
          f32x4 acc2[2] = {zero, zero};
          #pragma unroll
          for (int ks = 0; ks < 8; ks++) {
            short8 a = ((const short8*)h1A)[ks * 64 + lane];
            acc2[0] = __builtin_amdgcn_mfma_f32_16x16x32_bf16(a, w2f[ks][0], acc2[0], 0, 0, 0);
            acc2[1] = __builtin_amdgcn_mfma_f32_16x16x32_bf16(a, w2f[ks][1], acc2[1], 0, 0, 0);
          }
          #pragma unroll
          for (int j = 0; j < 2; j++) {
            int c = (wave * 2 + j) * 16 + cl;
            int boff = (c >> 5) * 512 + ((c & 31) >> 3) * 128 + (c & 7);
            #pragma unroll
            for (int reg = 0; reg < 4; reg++)
              h2A[boff + (4 * qd + reg) * 8] = bf16rne(tanh_fast(acc2[j][reg] + b2r[j]));
          }
        }
        __syncthreads();

        // ---- layer 3: f = h2 @ W3 + b3, K split across wave pairs
        {
          f32x4 acc3 = {0.f, 0.f, 0.f, 0.f};
          #pragma unroll
          for (int kk = 0; kk < 4; kk++) {
            short8 a = ((const short8*)h2A)[(ksb + kk) * 64 + lane];
            acc3 = __builtin_amdgcn_mfma_f32_16x16x32_bf16(a, w3f[kk], acc3, 0, 0, 0);
          }
          int c = w4 * 16 + cl;
          float* fb = (wave < 4) ? fbufA : fbufB;
          #pragma unroll
          for (int reg = 0; reg < 4; reg++)
            fb[(4 * qd + reg) * 68 + c] = acc3[reg] + b3r;
        }
        __syncthreads();

        // ---- phase 5: k_s = fbufA + fbufB back to registers (fp32)
        {
          float2 va = *(const float2*)(fbufA + rown * 68 + d0);
          float2 vb = *(const float2*)(fbufB + rown * 68 + d0);
          k[s][0] = va.x + vb.x;
          k[s][1] = va.y + vb.y;
        }
      } // stages

      #pragma unroll
      for (int i = 0; i < 2; i++) {
        float d = BW0 * k[0][i] + BW2 * k[2][i] + BW3 * k[3][i] +
                  BW4 * k[4][i] + BW5 * k[5][i];
        y[i] += hstep * d;
      }
    } // steps
  } // bijectors

  float2 o2; o2.x = y[0]; o2.y = y[1];
  *(float2*)(out + (row0 + rown) * 64 + d0) = o2;
}

extern "C" void kernel_launch(void* const* d_in, const int* in_sizes, int n_in,
                              void* d_out, int out_size, void* d_ws, size_t ws_size,
                              hipStream_t stream) {
  (void)in_sizes; (void)n_in; (void)out_size; (void)ws_size;
  const float* x   = (const float*)d_in[0];
  const float* W1a = (const float*)d_in[1];
  const float* b1a = (const float*)d_in[2];
  const float* W2a = (const float*)d_in[3];
  const float* b2a = (const float*)d_in[4];
  const float* W3a = (const float*)d_in[5];
  const float* b3a = (const float*)d_in[6];
  const float* W1b = (const float*)d_in[7];
  const float* b1b = (const float*)d_in[8];
  const float* W2b = (const float*)d_in[9];
  const float* b2b = (const float*)d_in[10];
  const float* W3b = (const float*)d_in[11];
  const float* b3b = (const float*)d_in[12];
  unsigned short* ws = (unsigned short*)d_ws;
  float* out = (float*)d_out;

  hipLaunchKernelGGL(ffjord_setup, dim3(96), dim3(256), 0, stream,
                     W1a, W2a, W3a, W1b, W2b, W3b, ws);
  hipLaunchKernelGGL(ffjord_main, dim3(256), dim3(512), 0, stream,
                     x, out, ws, W1a, b1a, b2a, b3a, W1b, b1b, b2b, b3b);
}

// Round 3
// 332.188 us; speedup vs baseline: 1.4631x; 1.0476x over previous
//
#include <hip/hip_runtime.h>

typedef __attribute__((ext_vector_type(8))) short short8;
typedef __attribute__((ext_vector_type(4))) float f32x4;

#define NSTEPS 16

__device__ __forceinline__ unsigned short bf16rne(float f) {
  unsigned int u = __float_as_uint(f);
  u += 0x7FFFu + ((u >> 16) & 1u);
  return (unsigned short)(u >> 16);
}

#if __has_builtin(__builtin_amdgcn_cvt_pk_bf16_f32)
typedef __attribute__((ext_vector_type(2))) __bf16 v2bf16;
__device__ __forceinline__ unsigned int pk2(float a, float b) {
  v2bf16 t = __builtin_amdgcn_cvt_pk_bf16_f32(a, b);
  unsigned int r;
  __builtin_memcpy(&r, &t, 4);
  return r;
}
#else
__device__ __forceinline__ unsigned int pk2(float a, float b) {
  unsigned int ua = __float_as_uint(a), ub = __float_as_uint(b);
  ua += 0x7FFFu + ((ua >> 16) & 1u);
  ub += 0x7FFFu + ((ub >> 16) & 1u);
  return (ua >> 16) | (ub & 0xFFFF0000u);
}
#endif

__device__ __forceinline__ float tanh_fast(float x) {
  // tanh(x) = 1 - 2/(e^{2x}+1); e->inf => 1, e->0 => -1 (no clamp needed)
  float e = __builtin_amdgcn_exp2f(x * 2.8853900817779268f);
  return __builtin_fmaf(-2.0f, __builtin_amdgcn_rcpf(e + 1.0f), 1.0f);
}

// Pre-shuffle fp32 weights -> bf16 MFMA fragments (B-frag of W == A-frag of W^T).
// lane holds W[k = 32*ks + 8*(lane>>4) + j][c = 16*t + (lane&15)], j=0..7
__global__ void ffjord_setup(const float* __restrict__ W1a, const float* __restrict__ W2a,
                             const float* __restrict__ W3a, const float* __restrict__ W1b,
                             const float* __restrict__ W2b, const float* __restrict__ W3b,
                             unsigned short* __restrict__ ws) {
  int gid = blockIdx.x * blockDim.x + threadIdx.x;   // 0..24575
  int bij = gid / 12288;
  int r = gid - bij * 12288;
  const float* W1 = bij ? W1b : W1a;
  const float* W2 = bij ? W2b : W2a;
  const float* W3 = bij ? W3b : W3a;
  unsigned short* o = ws + bij * 98304;
  const float* src;
  int kstride;
  if (r < 2048) {                 // W1f
    int lane = r & 63, nt = (r >> 6) & 15, ks = r >> 10;
    int k0 = ks * 32 + (lane >> 4) * 8, n = nt * 16 + (lane & 15);
    src = W1 + k0 * 256 + n; kstride = 256; o += r * 8;
  } else if (r < 10240) {         // W2f
    int rr = r - 2048;
    int lane = rr & 63, nt = (rr >> 6) & 15, ks = rr >> 10;
    int k0 = ks * 32 + (lane >> 4) * 8, n = nt * 16 + (lane & 15);
    src = W2 + k0 * 256 + n; kstride = 256; o += 16384 + rr * 8;
  } else {                        // W3f
    int rr = r - 10240;
    int lane = rr & 63, nt = (rr >> 6) & 3, ks = rr >> 8;
    int k0 = ks * 32 + (lane >> 4) * 8, n = nt * 16 + (lane & 15);
    src = W3 + k0 * 64 + n; kstride = 64; o += 81920 + rr * 8;
  }
  #pragma unroll
  for (int j = 0; j < 8; j++) o[j] = bf16rne(src[j * kstride]);
}

// Transposed GEMM: A = weight frags (M = hidden), B = activation frags (N = 16 batch rows).
// C-layout row=4*qd+reg = hidden idx -> each thread's 4 outputs are 4 consecutive k of the
// next layer's B-frag => single ds_write_b64 per tile. 512 threads, 8 waves, 2 m-tiles/wave.
__global__ __launch_bounds__(512, 2) void ffjord_main(
    const float* __restrict__ x, float* __restrict__ out,
    const unsigned short* __restrict__ ws,
    const float* __restrict__ W1a, const float* __restrict__ b1a,
    const float* __restrict__ b2a, const float* __restrict__ b3a,
    const float* __restrict__ W1b, const float* __restrict__ b1b,
    const float* __restrict__ b2b, const float* __restrict__ b3b) {
  // zA: [ks2][q4] groups of (16 rows x 8 j) ushorts, each group padded 256B->272B (136 ushorts)
  __shared__ __align__(16) unsigned short zA[1088];
  __shared__ __align__(16) unsigned short h1A[4096];   // [ks8][q4][row16][j8]
  __shared__ __align__(16) unsigned short h2A[4096];
  __shared__ __align__(16) float fbuf[2][16 * 68];     // L3 K-half partials, row stride 68

  const int tid = threadIdx.x;
  const int wave = tid >> 6;        // 0..7
  const int lane = tid & 63;
  const int cl = lane & 15;
  const int qd = lane >> 4;
  const int kh = wave >> 2;         // L3 K-half
  const int mt3 = wave & 3;         // L3 m-tile
  const int c3 = mt3 * 16 + qd * 4; // L3 output base dim
  const int row0 = blockIdx.x * 16;
  const int row = tid >> 5;         // batch row owned for state (0..15)
  const int d0 = (tid & 31) * 2;    // 2 state dims owned

  // z write offset (ushort units, padded groups)
  const int zoff = ((d0 >> 5) * 4 + ((d0 >> 3) & 3)) * 136 + row * 8 + (d0 & 7);
  // zB-frag read base for this lane (ks via +544 ushorts)
  const int zrb = qd * 136 + cl * 8;

  // h1A/h2A write offsets per m-tile (4 consecutive ushorts, 8B aligned)
  int hoff[2];
  #pragma unroll
  for (int t = 0; t < 2; t++) {
    int c0 = (wave * 2 + t) * 16 + qd * 4;
    hoff[t] = (c0 >> 5) * 512 + ((c0 & 31) >> 3) * 128 + cl * 8 + (c0 & 7);
  }

  const float hstep = 1.0f / 16.0f;

  float y[2];
  {
    float2 v = *(const float2*)(x + (row0 + row) * 64 + d0);
    y[0] = v.x; y[1] = v.y;
  }
  float k[6][2];

  const float ACO[6][5] = {
      {0.f, 0.f, 0.f, 0.f, 0.f},
      {1.f / 5.f, 0.f, 0.f, 0.f, 0.f},
      {3.f / 40.f, 9.f / 40.f, 0.f, 0.f, 0.f},
      {44.f / 45.f, -56.f / 15.f, 32.f / 9.f, 0.f, 0.f},
      {19372.f / 6561.f, -25360.f / 2187.f, 64448.f / 6561.f, -212.f / 729.f, 0.f},
      {9017.f / 3168.f, -355.f / 33.f, 46732.f / 5247.f, 49.f / 176.f, -5103.f / 18656.f}};
  const float CT[6] = {0.0f, 0.2f, 0.3f, 0.8f, 8.0f / 9.0f, 1.0f};
  const float BW0 = 35.f / 384.f, BW2 = 500.f / 1113.f, BW3 = 125.f / 192.f,
              BW4 = -2187.f / 6784.f, BW5 = 11.f / 84.f;

  for (int bij = 0; bij < 2; bij++) {
    const unsigned short* wsb = ws + bij * 98304;
    const float* W1 = bij ? W1b : W1a;
    const float* b1 = bij ? b1b : b1a;
    const float* b2 = bij ? b2b : b2a;
    const float* b3 = bij ? b3b : b3a;

    // per-thread bias/t-row vectors for this wave's hidden slots (4 consecutive dims)
    f32x4 b1c[2], w1t4[2], b2c[2];
    #pragma unroll
    for (int t = 0; t < 2; t++) {
      int c0 = (wave * 2 + t) * 16 + qd * 4;
      b1c[t] = *(const f32x4*)(b1 + c0);
      w1t4[t] = *(const f32x4*)(W1 + 64 * 256 + c0);
      b2c[t] = *(const f32x4*)(b2 + c0);
    }
    f32x4 b3c;
    if (kh == 0) b3c = *(const f32x4*)(b3 + c3);
    else { b3c[0] = 0.f; b3c[1] = 0.f; b3c[2] = 0.f; b3c[3] = 0.f; }

    // register-resident weight fragments (A-operand of W^T)
    const short8* w1p = (const short8*)wsb;
    const short8* w2p = (const short8*)(wsb + 16384);
    const short8* w3p = (const short8*)(wsb + 81920);
    short8 w1f[2][2];
    #pragma unroll
    for (int ks = 0; ks < 2; ks++)
      #pragma unroll
      for (int t = 0; t < 2; t++)
        w1f[ks][t] = w1p[(ks * 16 + wave * 2 + t) * 64 + lane];
    short8 w2f[8][2];
    #pragma unroll
    for (int ks = 0; ks < 8; ks++)
      #pragma unroll
      for (int t = 0; t < 2; t++)
        w2f[ks][t] = w2p[(ks * 16 + wave * 2 + t) * 64 + lane];
    short8 w3f[4];
    #pragma unroll
    for (int kk = 0; kk < 4; kk++)
      w3f[kk] = w3p[((kh * 4 + kk) * 4 + mt3) * 64 + lane];

    for (int step = 0; step < NSTEPS; step++) {
      float stepf = (float)step;
      #pragma unroll
      for (int s = 0; s < 6; s++) {
        float ts = (stepf + CT[s]) * hstep;

        // ---- phase 1: z = y + h*sum(a_sj * k_j) -> bf16 pair -> one b32 LDS write
        {
          float z0 = y[0], z1 = y[1];
          #pragma unroll
          for (int j = 0; j < 5; j++)
            if (j < s) {
              float a = hstep * ACO[s][j];
              z0 += a * k[j][0];
              z1 += a * k[j][1];
            }
          *(unsigned int*)(zA + zoff) = pk2(z0, z1);
        }
        __syncthreads();

        // ---- layer 1: h1 = tanh(W1^T z + b1 + t*W1t), K=64
        {
          short8 a0 = *(const short8*)(zA + zrb);
          short8 a1 = *(const short8*)(zA + zrb + 544);
          #pragma unroll
          for (int t = 0; t < 2; t++) {
            f32x4 acc;
            #pragma unroll
            for (int r = 0; r < 4; r++)
              acc[r] = __builtin_fmaf(ts, w1t4[t][r], b1c[t][r]);
            acc = __builtin_amdgcn_mfma_f32_16x16x32_bf16(w1f[0][t], a0, acc, 0, 0, 0);
            acc = __builtin_amdgcn_mfma_f32_16x16x32_bf16(w1f[1][t], a1, acc, 0, 0, 0);
            uint2 pv;
            pv.x = pk2(tanh_fast(acc[0]), tanh_fast(acc[1]));
            pv.y = pk2(tanh_fast(acc[2]), tanh_fast(acc[3]));
            *(uint2*)(h1A + hoff[t]) = pv;
          }
        }
        __syncthreads();

        // ---- layer 2: h2 = tanh(W2^T h1 + b2), K=256, 2 chains of 4 per tile
        {
          f32x4 accA[2], accB[2];
          #pragma unroll
          for (int t = 0; t < 2; t++) {
            accA[t] = b2c[t];
            accB[t][0] = 0.f; accB[t][1] = 0.f; accB[t][2] = 0.f; accB[t][3] = 0.f;
          }
          #pragma unroll
          for (int ks = 0; ks < 4; ks++) {
            short8 hb = ((const short8*)h1A)[ks * 64 + lane];
            accA[0] = __builtin_amdgcn_mfma_f32_16x16x32_bf16(w2f[ks][0], hb, accA[0], 0, 0, 0);
            accA[1] = __builtin_amdgcn_mfma_f32_16x16x32_bf16(w2f[ks][1], hb, accA[1], 0, 0, 0);
          }
          #pragma unroll
          for (int ks = 4; ks < 8; ks++) {
            short8 hb = ((const short8*)h1A)[ks * 64 + lane];
            accB[0] = __builtin_amdgcn_mfma_f32_16x16x32_bf16(w2f[ks][0], hb, accB[0], 0, 0, 0);
            accB[1] = __builtin_amdgcn_mfma_f32_16x16x32_bf16(w2f[ks][1], hb, accB[1], 0, 0, 0);
          }
          #pragma unroll
          for (int t = 0; t < 2; t++) {
            uint2 pv;
            pv.x = pk2(tanh_fast(accA[t][0] + accB[t][0]), tanh_fast(accA[t][1] + accB[t][1]));
            pv.y = pk2(tanh_fast(accA[t][2] + accB[t][2]), tanh_fast(accA[t][3] + accB[t][3]));
            *(uint2*)(h2A + hoff[t]) = pv;
          }
        }
        __syncthreads();

        // ---- layer 3: f = W3^T h2 + b3, K-half per wave group, 2 chains of 2
        {
          f32x4 accP = b3c;
          f32x4 accQ; accQ[0] = 0.f; accQ[1] = 0.f; accQ[2] = 0.f; accQ[3] = 0.f;
          short8 hb0 = ((const short8*)h2A)[(kh * 4 + 0) * 64 + lane];
          short8 hb1 = ((const short8*)h2A)[(kh * 4 + 1) * 64 + lane];
          short8 hb2 = ((const short8*)h2A)[(kh * 4 + 2) * 64 + lane];
          short8 hb3 = ((const short8*)h2A)[(kh * 4 + 3) * 64 + lane];
          accP = __builtin_amdgcn_mfma_f32_16x16x32_bf16(w3f[0], hb0, accP, 0, 0, 0);
          accP = __builtin_amdgcn_mfma_f32_16x16x32_bf16(w3f[1], hb1, accP, 0, 0, 0);
          accQ = __builtin_amdgcn_mfma_f32_16x16x32_bf16(w3f[2], hb2, accQ, 0, 0, 0);
          accQ = __builtin_amdgcn_mfma_f32_16x16x32_bf16(w3f[3], hb3, accQ, 0, 0, 0);
          f32x4 res;
          #pragma unroll
          for (int r = 0; r < 4; r++) res[r] = accP[r] + accQ[r];
          *(f32x4*)(&fbuf[kh][cl * 68 + c3]) = res;
        }
        __syncthreads();

        // ---- readback: k_s = fbuf[0] + fbuf[1]
        {
          float2 fa = *(const float2*)(&fbuf[0][row * 68 + d0]);
          float2 fb = *(const float2*)(&fbuf[1][row * 68 + d0]);
          k[s][0] = fa.x + fb.x;
          k[s][1] = fa.y + fb.y;
        }
      } // stages

      #pragma unroll
      for (int i = 0; i < 2; i++) {
        float d = BW0 * k[0][i] + BW2 * k[2][i] + BW3 * k[3][i] +
                  BW4 * k[4][i] + BW5 * k[5][i];
        y[i] += hstep * d;
      }
    } // steps
  } // bijectors

  float2 o2; o2.x = y[0]; o2.y = y[1];
  *(float2*)(out + (row0 + row) * 64 + d0) = o2;
}

extern "C" void kernel_launch(void* const* d_in, const int* in_sizes, int n_in,
                              void* d_out, int out_size, void* d_ws, size_t ws_size,
                              hipStream_t stream) {
  (void)in_sizes; (void)n_in; (void)out_size; (void)ws_size;
  const float* x   = (const float*)d_in[0];
  const float* W1a = (const float*)d_in[1];
  const float* b1a = (const float*)d_in[2];
  const float* W2a = (const float*)d_in[3];
  const float* b2a = (const float*)d_in[4];
  const float* W3a = (const float*)d_in[5];
  const float* b3a = (const float*)d_in[6];
  const float* W1b = (const float*)d_in[7];
  const float* b1b = (const float*)d_in[8];
  const float* W2b = (const float*)d_in[9];
  const float* b2b = (const float*)d_in[10];
  const float* W3b = (const float*)d_in[11];
  const float* b3b = (const float*)d_in[12];
  unsigned short* ws = (unsigned short*)d_ws;
  float* out = (float*)d_out;

  hipLaunchKernelGGL(ffjord_setup, dim3(96), dim3(256), 0, stream,
                     W1a, W2a, W3a, W1b, W2b, W3b, ws);
  hipLaunchKernelGGL(ffjord_main, dim3(256), dim3(512), 0, stream,
                     x, out, ws, W1a, b1a, b2a, b3a, W1b, b1b, b2b, b3b);
}

// Round 4
// 327.127 us; speedup vs baseline: 1.4857x; 1.0155x over previous
//
#include <hip/hip_runtime.h>

typedef __attribute__((ext_vector_type(8))) short short8;
typedef __attribute__((ext_vector_type(4))) float f32x4;

#define NSTEPS 16

__device__ __forceinline__ unsigned short bf16rne(float f) {
  unsigned int u = __float_as_uint(f);
  u += 0x7FFFu + ((u >> 16) & 1u);
  return (unsigned short)(u >> 16);
}

#if __has_builtin(__builtin_amdgcn_cvt_pk_bf16_f32)
typedef __attribute__((ext_vector_type(2))) __bf16 v2bf16;
__device__ __forceinline__ unsigned int pk2(float a, float b) {
  v2bf16 t = __builtin_amdgcn_cvt_pk_bf16_f32(a, b);
  unsigned int r;
  __builtin_memcpy(&r, &t, 4);
  return r;
}
#else
__device__ __forceinline__ unsigned int pk2(float a, float b) {
  unsigned int ua = __float_as_uint(a), ub = __float_as_uint(b);
  ua += 0x7FFFu + ((ua >> 16) & 1u);
  ub += 0x7FFFu + ((ub >> 16) & 1u);
  return (ua >> 16) | (ub & 0xFFFF0000u);
}
#endif

__device__ __forceinline__ float tanh_fast(float x) {
  // tanh(x) = 1 - 2/(e^{2x}+1); e->inf => 1, e->0 => -1 (no clamp needed)
  float e = __builtin_amdgcn_exp2f(x * 2.8853900817779268f);
  return __builtin_fmaf(-2.0f, __builtin_amdgcn_rcpf(e + 1.0f), 1.0f);
}

// Pre-shuffle fp32 weights -> bf16 MFMA fragments (B-frag of W == A-frag of W^T).
// lane holds W[k = 32*ks + 8*(lane>>4) + j][c = 16*t + (lane&15)], j=0..7
__global__ void ffjord_setup(const float* __restrict__ W1a, const float* __restrict__ W2a,
                             const float* __restrict__ W3a, const float* __restrict__ W1b,
                             const float* __restrict__ W2b, const float* __restrict__ W3b,
                             unsigned short* __restrict__ ws) {
  int gid = blockIdx.x * blockDim.x + threadIdx.x;   // 0..24575
  int bij = gid / 12288;
  int r = gid - bij * 12288;
  const float* W1 = bij ? W1b : W1a;
  const float* W2 = bij ? W2b : W2a;
  const float* W3 = bij ? W3b : W3a;
  unsigned short* o = ws + bij * 98304;
  const float* src;
  int kstride;
  if (r < 2048) {                 // W1f
    int lane = r & 63, nt = (r >> 6) & 15, ks = r >> 10;
    int k0 = ks * 32 + (lane >> 4) * 8, n = nt * 16 + (lane & 15);
    src = W1 + k0 * 256 + n; kstride = 256; o += r * 8;
  } else if (r < 10240) {         // W2f
    int rr = r - 2048;
    int lane = rr & 63, nt = (rr >> 6) & 15, ks = rr >> 10;
    int k0 = ks * 32 + (lane >> 4) * 8, n = nt * 16 + (lane & 15);
    src = W2 + k0 * 256 + n; kstride = 256; o += 16384 + rr * 8;
  } else {                        // W3f
    int rr = r - 10240;
    int lane = rr & 63, nt = (rr >> 6) & 3, ks = rr >> 8;
    int k0 = ks * 32 + (lane >> 4) * 8, n = nt * 16 + (lane & 15);
    src = W3 + k0 * 64 + n; kstride = 64; o += 81920 + rr * 8;
  }
  #pragma unroll
  for (int j = 0; j < 8; j++) o[j] = bf16rne(src[j * kstride]);
}

// 1024 threads / 16 waves per block, 16 batch rows. Wave w owns m-tile w of
// layers 1/2 (weights register-resident); L3 = 4 m-tiles x 4 K-quarters with
// 4 fp32 partial buffers. State: 1 element/thread (row = wave, dim = lane).
__global__ __launch_bounds__(1024, 4) void ffjord_main(
    const float* __restrict__ x, float* __restrict__ out,
    const unsigned short* __restrict__ ws,
    const float* __restrict__ W1a, const float* __restrict__ b1a,
    const float* __restrict__ b2a, const float* __restrict__ b3a,
    const float* __restrict__ W1b, const float* __restrict__ b1b,
    const float* __restrict__ b2b, const float* __restrict__ b3b) {
  // zA: [ks2][q4] groups of (16 rows x 8 j) ushorts, each group padded 256B->272B
  __shared__ __align__(16) unsigned short zA[1088];
  __shared__ __align__(16) unsigned short h1A[4096];   // [ks8][q4][row16][j8]
  __shared__ __align__(16) unsigned short h2A[4096];
  __shared__ __align__(16) float fbuf[4][16 * 68];     // L3 K-quarter partials

  const int tid = threadIdx.x;
  const int wave = tid >> 6;        // 0..15
  const int lane = tid & 63;
  const int cl = lane & 15;
  const int qd = lane >> 4;
  const int mt3 = wave & 3;         // L3 m-tile
  const int kq = wave >> 2;         // L3 K-quarter
  const int c3 = mt3 * 16 + qd * 4; // L3 output base dim
  const int row0 = blockIdx.x * 16;
  const int row = wave;             // batch row owned for state
  const int d0 = lane;              // state dim owned

  // z write offset (ushort units, padded groups)
  const int zoff = ((d0 >> 5) * 4 + ((d0 >> 3) & 3)) * 136 + row * 8 + (d0 & 7);
  // zB-frag read base for this lane (ks via +544 ushorts)
  const int zrb = qd * 136 + cl * 8;
  // L1/L2 output tile: wave w owns hidden dims [w*16, w*16+16)
  const int c0 = wave * 16 + qd * 4;
  const int hoff = (c0 >> 5) * 512 + ((c0 & 31) >> 3) * 128 + cl * 8 + (c0 & 7);

  const float hstep = 1.0f / 16.0f;

  float y = x[(row0 + row) * 64 + d0];
  float k[6];

  const float ACO[6][5] = {
      {0.f, 0.f, 0.f, 0.f, 0.f},
      {1.f / 5.f, 0.f, 0.f, 0.f, 0.f},
      {3.f / 40.f, 9.f / 40.f, 0.f, 0.f, 0.f},
      {44.f / 45.f, -56.f / 15.f, 32.f / 9.f, 0.f, 0.f},
      {19372.f / 6561.f, -25360.f / 2187.f, 64448.f / 6561.f, -212.f / 729.f, 0.f},
      {9017.f / 3168.f, -355.f / 33.f, 46732.f / 5247.f, 49.f / 176.f, -5103.f / 18656.f}};
  const float CT[6] = {0.0f, 0.2f, 0.3f, 0.8f, 8.0f / 9.0f, 1.0f};
  const float BW0 = 35.f / 384.f, BW2 = 500.f / 1113.f, BW3 = 125.f / 192.f,
              BW4 = -2187.f / 6784.f, BW5 = 11.f / 84.f;

  for (int bij = 0; bij < 2; bij++) {
    const unsigned short* wsb = ws + bij * 98304;
    const float* W1 = bij ? W1b : W1a;
    const float* b1 = bij ? b1b : b1a;
    const float* b2 = bij ? b2b : b2a;
    const float* b3 = bij ? b3b : b3a;

    // per-thread bias/t-row vectors for this wave's hidden slots
    f32x4 b1c = *(const f32x4*)(b1 + c0);
    f32x4 w1t4 = *(const f32x4*)(W1 + 64 * 256 + c0);
    f32x4 b2c = *(const f32x4*)(b2 + c0);
    f32x4 b3c;
    if (kq == 0) b3c = *(const f32x4*)(b3 + c3);
    else { b3c[0] = 0.f; b3c[1] = 0.f; b3c[2] = 0.f; b3c[3] = 0.f; }

    // register-resident weight fragments (A-operand of W^T)
    const short8* w1p = (const short8*)wsb;
    const short8* w2p = (const short8*)(wsb + 16384);
    const short8* w3p = (const short8*)(wsb + 81920);
    short8 w1f[2];
    #pragma unroll
    for (int ks = 0; ks < 2; ks++)
      w1f[ks] = w1p[(ks * 16 + wave) * 64 + lane];
    short8 w2f[8];
    #pragma unroll
    for (int ks = 0; ks < 8; ks++)
      w2f[ks] = w2p[(ks * 16 + wave) * 64 + lane];
    short8 w3f[2];
    #pragma unroll
    for (int kk = 0; kk < 2; kk++)
      w3f[kk] = w3p[((kq * 2 + kk) * 4 + mt3) * 64 + lane];

    for (int step = 0; step < NSTEPS; step++) {
      float stepf = (float)step;
      #pragma unroll
      for (int s = 0; s < 6; s++) {
        float ts = (stepf + CT[s]) * hstep;

        // ---- phase 1: z = y + h*sum(a_sj * k_j) -> bf16 -> one b16 LDS write
        {
          float z = y;
          #pragma unroll
          for (int j = 0; j < 5; j++)
            if (j < s) z += (hstep * ACO[s][j]) * k[j];
          zA[zoff] = bf16rne(z);
        }
        __syncthreads();

        // ---- layer 1: h1 = tanh(W1^T z + b1 + t*W1t), K=64, one m-tile/wave
        {
          short8 a0 = *(const short8*)(zA + zrb);
          short8 a1 = *(const short8*)(zA + zrb + 544);
          f32x4 acc;
          #pragma unroll
          for (int r = 0; r < 4; r++)
            acc[r] = __builtin_fmaf(ts, w1t4[r], b1c[r]);
          acc = __builtin_amdgcn_mfma_f32_16x16x32_bf16(w1f[0], a0, acc, 0, 0, 0);
          acc = __builtin_amdgcn_mfma_f32_16x16x32_bf16(w1f[1], a1, acc, 0, 0, 0);
          uint2 pv;
          pv.x = pk2(tanh_fast(acc[0]), tanh_fast(acc[1]));
          pv.y = pk2(tanh_fast(acc[2]), tanh_fast(acc[3]));
          *(uint2*)(h1A + hoff) = pv;
        }
        __syncthreads();

        // ---- layer 2: h2 = tanh(W2^T h1 + b2), K=256, 2 chains of 4
        {
          f32x4 accA = b2c;
          f32x4 accB; accB[0] = 0.f; accB[1] = 0.f; accB[2] = 0.f; accB[3] = 0.f;
          #pragma unroll
          for (int ks = 0; ks < 4; ks++) {
            short8 hb = ((const short8*)h1A)[ks * 64 + lane];
            accA = __builtin_amdgcn_mfma_f32_16x16x32_bf16(w2f[ks], hb, accA, 0, 0, 0);
          }
          #pragma unroll
          for (int ks = 4; ks < 8; ks++) {
            short8 hb = ((const short8*)h1A)[ks * 64 + lane];
            accB = __builtin_amdgcn_mfma_f32_16x16x32_bf16(w2f[ks], hb, accB, 0, 0, 0);
          }
          uint2 pv;
          pv.x = pk2(tanh_fast(accA[0] + accB[0]), tanh_fast(accA[1] + accB[1]));
          pv.y = pk2(tanh_fast(accA[2] + accB[2]), tanh_fast(accA[3] + accB[3]));
          *(uint2*)(h2A + hoff) = pv;
        }
        __syncthreads();

        // ---- layer 3: f = W3^T h2 + b3, K-quarter per wave group
        {
          short8 hb0 = ((const short8*)h2A)[(kq * 2 + 0) * 64 + lane];
          short8 hb1 = ((const short8*)h2A)[(kq * 2 + 1) * 64 + lane];
          f32x4 accP = b3c;
          accP = __builtin_amdgcn_mfma_f32_16x16x32_bf16(w3f[0], hb0, accP, 0, 0, 0);
          accP = __builtin_amdgcn_mfma_f32_16x16x32_bf16(w3f[1], hb1, accP, 0, 0, 0);
          *(f32x4*)(&fbuf[kq][cl * 68 + c3]) = accP;
        }
        __syncthreads();

        // ---- readback: k_s = sum of 4 partials
        {
          int fo = row * 68 + d0;
          k[s] = (fbuf[0][fo] + fbuf[1][fo]) + (fbuf[2][fo] + fbuf[3][fo]);
        }
      } // stages

      y += hstep * (BW0 * k[0] + BW2 * k[2] + BW3 * k[3] + BW4 * k[4] + BW5 * k[5]);
    } // steps
  } // bijectors

  out[(row0 + row) * 64 + d0] = y;
}

extern "C" void kernel_launch(void* const* d_in, const int* in_sizes, int n_in,
                              void* d_out, int out_size, void* d_ws, size_t ws_size,
                              hipStream_t stream) {
  (void)in_sizes; (void)n_in; (void)out_size; (void)ws_size;
  const float* x   = (const float*)d_in[0];
  const float* W1a = (const float*)d_in[1];
  const float* b1a = (const float*)d_in[2];
  const float* W2a = (const float*)d_in[3];
  const float* b2a = (const float*)d_in[4];
  const float* W3a = (const float*)d_in[5];
  const float* b3a = (const float*)d_in[6];
  const float* W1b = (const float*)d_in[7];
  const float* b1b = (const float*)d_in[8];
  const float* W2b = (const float*)d_in[9];
  const float* b2b = (const float*)d_in[10];
  const float* W3b = (const float*)d_in[11];
  const float* b3b = (const float*)d_in[12];
  unsigned short* ws = (unsigned short*)d_ws;
  float* out = (float*)d_out;

  hipLaunchKernelGGL(ffjord_setup, dim3(96), dim3(256), 0, stream,
                     W1a, W2a, W3a, W1b, W2b, W3b, ws);
  hipLaunchKernelGGL(ffjord_main, dim3(256), dim3(1024), 0, stream,
                     x, out, ws, W1a, b1a, b2a, b3a, W1b, b1b, b2b, b3b);
}